// Round 9
// baseline (403.211 us; speedup 1.0000x reference)
//
#include <hip/hip_runtime.h>
#include <math.h>

#define D_MODEL 256
#define N_EXP   16
#define N_VIEWS 3
#define N_TOK   8192
#define TOPK    4
#define HDIM    1024
#define CH      64
#define NCH     16
#define ROWS    64             // rows per ffn tile
#define NGROUP  48
#define GCAP    8192           // fixed capacity per (view,expert) group
#define REC_ELTS 32768         // chunk record: W1 half (16384) + W2 half (16384) shorts

typedef short s16x8 __attribute__((ext_vector_type(8)));
typedef float f32x4 __attribute__((ext_vector_type(4)));

__device__ __forceinline__ unsigned short f2bf(float x) {
    union { float f; unsigned u; } a; a.f = x;
    unsigned r = a.u + 0x7FFFu + ((a.u >> 16) & 1u);   // RNE
    return (unsigned short)(r >> 16);
}

// async global -> LDS, 16 B per lane; LDS dst is wave-uniform base + lane*16
__device__ __forceinline__ void dma16(const unsigned short* gp, unsigned short* lp) {
    __builtin_amdgcn_global_load_lds(
        (const __attribute__((address_space(1))) unsigned int*)gp,
        (__attribute__((address_space(3))) unsigned int*)lp, 16, 0, 0);
}

// stage one 32 KB half-record: 8 waves x 4 instr x 1 KB
__device__ __forceinline__ void dma_half(const unsigned short* gsrc, unsigned short* ldst,
                                         int wave, int lane) {
    #pragma unroll
    for (int i = 0; i < 4; i++) {
        int blk = wave * 4 + i;                       // 0..31, 1 KB blocks
        dma16(gsrc + ((size_t)blk * 64 + lane) * 8, ldst + blk * 512);
    }
}

// ------------------------------------------------------------------
// fused prep: blocks [0,512) build Wf fragment records via coalesced
// LDS-transpose (wfrag role); blocks [512,896) do routing + group fill
// (route role). Independent work, one launch; scan/fill kernels removed.
//
// W1 half: idx=(ks*4+nt)*64+lane : elem = W1[e][ks*32+(lane>>4)*8+j][c*64+nt*16+(lane&15)]
// W2 half: idx=(ks2*16+nt)*64+lane: elem = W2[e][c*64+ks2*32+(lane>>4)*8+j][nt*16+(lane&15)]
// ------------------------------------------------------------------
#define T1_STRIDE 65    // 256 x 65 f32 = 66560 B
#define T2_STRIDE 257   // 64 x 257 f32 = 65792 B

__global__ __launch_bounds__(256) void prep_kernel(
    const float* __restrict__ v0, const float* __restrict__ v1, const float* __restrict__ v2,
    const float* __restrict__ rw, const float* __restrict__ keys,
    const float* __restrict__ W1, const float* __restrict__ W2,
    unsigned short* __restrict__ Wf, unsigned short* __restrict__ Xbf,
    int* __restrict__ counts, int* __restrict__ rowTok, float* __restrict__ rowGate)
{
    __shared__ __align__(16) char smem[256 * T1_STRIDE * 4];   // 66560 B, role-unioned

    int bid = blockIdx.x;
    int tid = threadIdx.x;
    if (bid < 512) {
        // ---- wfrag role ----
        int c = bid & 15, e = (bid >> 4) & 15, z = bid >> 8;
        unsigned short* dst = Wf + (size_t)(e * NCH + c) * REC_ELTS;
        if (z == 0) {
            float* T1 = (float*)smem;
            const float* src = W1 + (size_t)e * 256 * 1024 + c * 64;
            #pragma unroll
            for (int p = 0; p < 16; p++) {
                int k = p * 16 + (tid >> 4), c4 = (tid & 15) * 4;
                float4 v = *(const float4*)(src + (size_t)k * 1024 + c4);
                T1[k * T1_STRIDE + c4]     = v.x;
                T1[k * T1_STRIDE + c4 + 1] = v.y;
                T1[k * T1_STRIDE + c4 + 2] = v.z;
                T1[k * T1_STRIDE + c4 + 3] = v.w;
            }
            __syncthreads();
            #pragma unroll
            for (int i = 0; i < 8; i++) {
                int idx = tid + i * 256;
                int lane = idx & 63, nt = (idx >> 6) & 3, ks = idx >> 8;
                int nl = nt * 16 + (lane & 15);
                int kbase = ks * 32 + (lane >> 4) * 8;
                s16x8 o;
                #pragma unroll
                for (int j = 0; j < 8; j++) o[j] = (short)f2bf(T1[(kbase + j) * T1_STRIDE + nl]);
                *(s16x8*)(dst + (size_t)idx * 8) = o;
            }
        } else {
            float* T2 = (float*)smem;
            const float* src = W2 + ((size_t)e * 1024 + c * 64) * 256;
            #pragma unroll
            for (int p = 0; p < 16; p++) {
                int k2l = p * 4 + (tid >> 6), c4 = (tid & 63) * 4;
                float4 v = *(const float4*)(src + (size_t)k2l * 256 + c4);
                T2[k2l * T2_STRIDE + c4]     = v.x;
                T2[k2l * T2_STRIDE + c4 + 1] = v.y;
                T2[k2l * T2_STRIDE + c4 + 2] = v.z;
                T2[k2l * T2_STRIDE + c4 + 3] = v.w;
            }
            __syncthreads();
            dst += 16384;
            #pragma unroll
            for (int i = 0; i < 8; i++) {
                int idx = tid + i * 256;
                int lane = idx & 63, ntile = (idx >> 6) & 15, ks2 = idx >> 10;
                int n = ntile * 16 + (lane & 15);
                int kbase = ks2 * 32 + (lane >> 4) * 8;
                s16x8 o;
                #pragma unroll
                for (int j = 0; j < 8; j++) o[j] = (short)f2bf(T2[(kbase + j) * T2_STRIDE + n]);
                *(s16x8*)(dst + (size_t)idx * 8) = o;
            }
        }
        return;
    }

    // ---- route + fill role: 64 tokens per block ----
    float* cwS  = (float*)smem;                      // 16 KB
    float* knS  = (float*)(smem + 16384);            // 64 B
    int*   lcnt = (int*)(smem + 16448);              // 64 B
    int*   eIdx = (int*)(smem + 16512);              // 1 KB: [tok_local*4+k]
    float* gV   = (float*)(smem + 17536);            // 1 KB
    int*  lbase = (int*)(smem + 18560);              // 64 B

    int rb = bid - 512;
    int view = rb >> 7, xb = rb & 127;
    const float* src = view == 0 ? v0 : (view == 1 ? v1 : v2);
    for (int i = tid; i < N_EXP * D_MODEL; i += 256)
        cwS[i] = rw[view * N_EXP * D_MODEL + i] + 2.0f * keys[i];
    if (tid < N_EXP) {
        const float4* kp = (const float4*)(keys + tid * D_MODEL);
        float s = 0.f;
        for (int d = 0; d < 64; d++) { float4 k = kp[d]; s += k.x*k.x + k.y*k.y + k.z*k.z + k.w*k.w; }
        knS[tid] = s; lcnt[tid] = 0;
    }
    __syncthreads();

    int wave = tid >> 6, lane = tid & 63;
    for (int t = 0; t < 16; t++) {
        int tl = wave * 16 + t;                      // token local 0..63
        int token = xb * 64 + tl;
        float4 v = ((const float4*)(src + (size_t)token * D_MODEL))[lane];
        ushort4 xo; xo.x = f2bf(v.x); xo.y = f2bf(v.y); xo.z = f2bf(v.z); xo.w = f2bf(v.w);
        ((ushort4*)(Xbf + ((size_t)view * N_TOK + token) * D_MODEL))[lane] = xo;
        float lg[N_EXP];
        #pragma unroll
        for (int e = 0; e < N_EXP; e++) {
            float4 w = *(const float4*)&cwS[e * D_MODEL + lane * 4];
            float p = v.x * w.x + v.y * w.y + v.z * w.z + v.w * w.w;
            #pragma unroll
            for (int s = 32; s > 0; s >>= 1) p += __shfl_xor(p, s, 64);
            lg[e] = p - knS[e];
        }
        int idxs[TOPK]; float vals[TOPK];
        #pragma unroll
        for (int k = 0; k < TOPK; k++) {
            float best = -1e30f; int bi = 0;
            #pragma unroll
            for (int e = 0; e < N_EXP; e++)
                if (lg[e] > best) { best = lg[e]; bi = e; }
            idxs[k] = bi; vals[k] = best;
            #pragma unroll
            for (int e = 0; e < N_EXP; e++)
                lg[e] = (e == bi) ? -1e30f : lg[e];
        }
        float m = vals[0], s = 0.f, ex[TOPK];
        #pragma unroll
        for (int k = 0; k < TOPK; k++) { ex[k] = __expf(vals[k] - m); s += ex[k]; }
        float inv = 1.0f / s;
        if (lane == 0) {
            #pragma unroll
            for (int k = 0; k < TOPK; k++) {
                eIdx[tl * 4 + k] = idxs[k];
                gV[tl * 4 + k] = ex[k] * inv;
                atomicAdd(&lcnt[idxs[k]], 1);
            }
        }
    }
    __syncthreads();
    // claim global ranges + scatter (threads 0..15 = experts)
    if (tid < N_EXP)
        lbase[tid] = lcnt[tid] ? atomicAdd(&counts[view * N_EXP + tid], lcnt[tid]) : 0;
    __syncthreads();
    if (tid < N_EXP) {
        int e = tid;
        int dstbase = (view * N_EXP + e) * GCAP + lbase[e];
        int c = 0;
        for (int i = 0; i < 256; i++) {
            if (eIdx[i] == e) {
                rowTok[dstbase + c]  = xb * 64 + (i >> 2);
                rowGate[dstbase + c] = gV[i];
                c++;
            }
        }
    }
}

// ------------------------------------------------------------------
// fused FFN (r5/r8 structure, proven 239 us / no spill): 1 block = 64 rows of
// one (view,expert) group; 512 thr, 8 waves. areg[8]=32 VGPR, acc2=32 AGPR.
// LDS 74240 B -> 2 blocks/CU. Async DMA one phase ahead, 2 barriers/chunk.
// STATIC schedule: xcd = blockIdx&7 owns experts {2x,2x+1} x 3 views;
// k = blockIdx>>3 -> (group j=k%6, tile=k/6); empty tiles exit on counts[g].
// ------------------------------------------------------------------
__global__ __launch_bounds__(512, 4) void ffn_kernel(
    const unsigned short* __restrict__ Xbf, const unsigned short* __restrict__ Wf,
    const float* __restrict__ b1, const float* __restrict__ b2,
    const int* __restrict__ counts, const int* __restrict__ rowTok,
    const float* __restrict__ rowGate, float* __restrict__ out)
{
    __shared__ __align__(16) unsigned short Wbuf[REC_ELTS];   // 64 KB: W1c | W2c
    __shared__ __align__(16) unsigned short Hc[ROWS * CH];    // 8 KB, A-frag order
    __shared__ int   tokS[ROWS];
    __shared__ float gateS[ROWS];

    int s = blockIdx.x;
    int xcd = s & 7, k = s >> 3;
    int j = k % 6, ti = k / 6;                 // j: group-of-xcd, ti: tile 0..127
    int e = 2 * xcd + (j & 1), view = j >> 1;
    int g = view * N_EXP + e;
    int L = counts[g];
    int r0 = ti * ROWS;
    if (r0 >= L) return;
    int base = g * GCAP;

    int tid = threadIdx.x;
    int wave = tid >> 6, lane = tid & 63, lmod = lane & 15, quad = lane >> 4;

    const unsigned short* wchunk = Wf + (size_t)e * NCH * REC_ELTS;
    dma_half(wchunk, Wbuf, wave, lane);          // W1[0]

    if (tid < ROWS) {
        int gr = r0 + tid; bool ok = gr < L;
        tokS[tid]  = ok ? rowTok[base + gr] : -1;
        gateS[tid] = ok ? rowGate[base + gr] : 0.f;
    }

    int mt1 = wave & 3, nh = wave >> 2;          // GEMM1 roles
    int ms  = wave & 1, ns = wave >> 1;          // GEMM2 roles

    __syncthreads();   // tokS ready; W1[0] landed (barrier drains vmcnt)

    // X A-fragments for m-tile mt1 (32 VGPR)
    s16x8 areg[8];
    {
        int token = tokS[mt1 * 16 + lmod];
        if (token < 0) token = 0;
        const unsigned short* xp = Xbf + ((size_t)view * N_TOK + token) * D_MODEL;
        #pragma unroll
        for (int ks = 0; ks < 8; ks++)
            areg[ks] = *(const s16x8*)(xp + ks * 32 + quad * 8);
    }
    dma_half(wchunk + 16384, Wbuf + 16384, wave, lane);   // W2[0], lands during GEMM1[0]

    f32x4 acc2[2][4];
    #pragma unroll
    for (int i = 0; i < 2; i++)
        #pragma unroll
        for (int jj = 0; jj < 4; jj++) acc2[i][jj] = (f32x4){0.f, 0.f, 0.f, 0.f};

    for (int c = 0; c < NCH; c++) {
        // ---- GEMM1: 16 rows x 32 cols per wave, K=256
        f32x4 acc1[2];
        acc1[0] = (f32x4){0.f, 0.f, 0.f, 0.f};
        acc1[1] = (f32x4){0.f, 0.f, 0.f, 0.f};
        #pragma unroll
        for (int ks = 0; ks < 8; ks++) {
            #pragma unroll
            for (int nt = 0; nt < 2; nt++) {
                s16x8 b = *(const s16x8*)&Wbuf[((ks * 4 + nh * 2 + nt) * 64 + lane) * 8];
                acc1[nt] = __builtin_amdgcn_mfma_f32_16x16x32_bf16(areg[ks], b, acc1[nt], 0, 0, 0);
            }
        }
        // ---- bias + gelu -> Hc (A-frag order for GEMM2)
        #pragma unroll
        for (int nt = 0; nt < 2; nt++) {
            float bb = b1[e * HDIM + c * CH + (nh * 2 + nt) * 16 + lmod];
            int qa = nt * 2 + (lmod >> 3);
            int baseo = ((mt1 * 2 + nh) * 64 + qa * 16 + quad * 4) * 8 + (lmod & 7);
            #pragma unroll
            for (int r = 0; r < 4; r++) {
                float h = acc1[nt][r] + bb;
                float u = h * (0.7978845608f + 0.0356774081f * h * h);
                float ex2 = __expf(2.f * u);
                float tn = 1.f - 2.f * __builtin_amdgcn_rcpf(1.f + ex2);
                Hc[baseo + r * 8] = f2bf(0.5f * h * (1.f + tn));
            }
        }
        __syncthreads();   // drains W2[c] DMA; Hc visible; GEMM1 done with W1 half
        if (c < NCH - 1)   // W1[c+1] (lands during GEMM2)
            dma_half(wchunk + (size_t)(c + 1) * REC_ELTS, Wbuf, wave, lane);
        // ---- GEMM2: 32 rows x 64 cols per wave, K=64
        #pragma unroll
        for (int ks2 = 0; ks2 < 2; ks2++) {
            s16x8 afr[2];
            #pragma unroll
            for (int mt = 0; mt < 2; mt++)
                afr[mt] = *(const s16x8*)&Hc[(((ms * 2 + mt) * 2 + ks2) * 64 + lane) * 8];
            #pragma unroll
            for (int nt = 0; nt < 4; nt++) {
                s16x8 b = *(const s16x8*)&Wbuf[16384 + ((ks2 * 16 + ns * 4 + nt) * 64 + lane) * 8];
                #pragma unroll
                for (int mt = 0; mt < 2; mt++)
                    acc2[mt][nt] = __builtin_amdgcn_mfma_f32_16x16x32_bf16(
                        afr[mt], b, acc2[mt][nt], 0, 0, 0);
            }
        }
        __syncthreads();   // drains W1[c+1] DMA; GEMM2 done with W2 half + Hc
        if (c < NCH - 1)   // W2[c+1] (lands during GEMM1[c+1]+gelu)
            dma_half(wchunk + (size_t)(c + 1) * REC_ELTS + 16384, Wbuf + 16384, wave, lane);
    }

    // epilogue: out[token] += gate * (acc2 + b2)
    #pragma unroll
    for (int nt = 0; nt < 4; nt++) {
        int col = (ns * 4 + nt) * 16 + lmod;
        float b2v = b2[e * D_MODEL + col];
        #pragma unroll
        for (int mt = 0; mt < 2; mt++) {
            #pragma unroll
            for (int r = 0; r < 4; r++) {
                int rloc = (ms * 2 + mt) * 16 + quad * 4 + r;
                if (r0 + rloc < L) {
                    atomicAdd(&out[(size_t)tokS[rloc] * D_MODEL + col],
                              gateS[rloc] * (acc2[mt][nt][r] + b2v));
                }
            }
        }
    }
}

// ------------------------------------------------------------------
extern "C" void kernel_launch(void* const* d_in, const int* in_sizes, int n_in,
                              void* d_out, int out_size, void* d_ws, size_t ws_size,
                              hipStream_t stream)
{
    const float* v0   = (const float*)d_in[0];
    const float* v1   = (const float*)d_in[1];
    const float* v2   = (const float*)d_in[2];
    const float* rw   = (const float*)d_in[3];
    const float* keys = (const float*)d_in[4];
    const float* W1   = (const float*)d_in[5];
    const float* b1   = (const float*)d_in[6];
    const float* W2   = (const float*)d_in[7];
    const float* b2   = (const float*)d_in[8];
    float* out = (float*)d_out;

    char* p = (char*)d_ws;
    unsigned short* Xbf = (unsigned short*)p; p += (size_t)N_VIEWS * N_TOK * D_MODEL * 2;
    unsigned short* Wf  = (unsigned short*)p; p += (size_t)N_EXP * NCH * REC_ELTS * 2;
    int*   counts = (int*)p;   p += 256;
    int*   rowTok = (int*)p;   p += (size_t)NGROUP * GCAP * 4;
    float* rowGate= (float*)p; p += (size_t)NGROUP * GCAP * 4;

    hipMemsetAsync(counts, 0, NGROUP * sizeof(int), stream);
    hipMemsetAsync(out, 0, (size_t)out_size * sizeof(float), stream);

    prep_kernel<<<896, 256, 0, stream>>>(v0, v1, v2, rw, keys, W1, W2,
                                         Wf, Xbf, counts, rowTok, rowGate);
    ffn_kernel<<<8 * 768, 512, 0, stream>>>(Xbf, Wf, b1, b2, counts,
                                            rowTok, rowGate, out);
}

// Round 10
// 389.354 us; speedup vs baseline: 1.0356x; 1.0356x over previous
//
#include <hip/hip_runtime.h>
#include <math.h>

#define D_MODEL 256
#define N_EXP   16
#define N_VIEWS 3
#define N_TOK   8192
#define TOPK    4
#define HDIM    1024
#define CH      64
#define NCH     16
#define ROWS    64             // rows per ffn tile
#define NGROUP  48
#define GCAP    8192           // fixed capacity per (view,expert) group
#define REC_ELTS 32768         // chunk record: W1 half (16384) + W2 half (16384) shorts

typedef short s16x8 __attribute__((ext_vector_type(8)));
typedef float f32x4 __attribute__((ext_vector_type(4)));

__device__ __forceinline__ unsigned short f2bf(float x) {
    union { float f; unsigned u; } a; a.f = x;
    unsigned r = a.u + 0x7FFFu + ((a.u >> 16) & 1u);   // RNE
    return (unsigned short)(r >> 16);
}

// async global -> LDS, 16 B per lane; LDS dst is wave-uniform base + lane*16
__device__ __forceinline__ void dma16(const unsigned short* gp, unsigned short* lp) {
    __builtin_amdgcn_global_load_lds(
        (const __attribute__((address_space(1))) unsigned int*)gp,
        (__attribute__((address_space(3))) unsigned int*)lp, 16, 0, 0);
}

// stage one 32 KB half-record: 8 waves x 4 instr x 1 KB
__device__ __forceinline__ void dma_half(const unsigned short* gsrc, unsigned short* ldst,
                                         int wave, int lane) {
    #pragma unroll
    for (int i = 0; i < 4; i++) {
        int blk = wave * 4 + i;                       // 0..31, 1 KB blocks
        dma16(gsrc + ((size_t)blk * 64 + lane) * 8, ldst + blk * 512);
    }
}

// ------------------------------------------------------------------
// fused prep: blocks [0,512) build Wf fragment records via coalesced
// LDS-transpose (wfrag role); blocks [512,896) do routing + group fill.
//
// W1 half: idx=(ks*4+nt)*64+lane : elem = W1[e][ks*32+(lane>>4)*8+j][c*64+nt*16+(lane&15)]
// W2 half: idx=(ks2*16+nt)*64+lane: elem = W2[e][c*64+ks2*32+(lane>>4)*8+j][nt*16+(lane&15)]
// ------------------------------------------------------------------
#define T1_STRIDE 65    // 256 x 65 f32 = 66560 B
#define T2_STRIDE 257   // 64 x 257 f32 = 65792 B

__global__ __launch_bounds__(256) void prep_kernel(
    const float* __restrict__ v0, const float* __restrict__ v1, const float* __restrict__ v2,
    const float* __restrict__ rw, const float* __restrict__ keys,
    const float* __restrict__ W1, const float* __restrict__ W2,
    unsigned short* __restrict__ Wf, unsigned short* __restrict__ Xbf,
    int* __restrict__ counts, int* __restrict__ rowTok, float* __restrict__ rowGate)
{
    __shared__ __align__(16) char smem[256 * T1_STRIDE * 4];   // 66560 B, role-unioned

    int bid = blockIdx.x;
    int tid = threadIdx.x;
    if (bid < 512) {
        // ---- wfrag role ----
        int c = bid & 15, e = (bid >> 4) & 15, z = bid >> 8;
        unsigned short* dst = Wf + (size_t)(e * NCH + c) * REC_ELTS;
        if (z == 0) {
            float* T1 = (float*)smem;
            const float* src = W1 + (size_t)e * 256 * 1024 + c * 64;
            #pragma unroll
            for (int p = 0; p < 16; p++) {
                int k = p * 16 + (tid >> 4), c4 = (tid & 15) * 4;
                float4 v = *(const float4*)(src + (size_t)k * 1024 + c4);
                T1[k * T1_STRIDE + c4]     = v.x;
                T1[k * T1_STRIDE + c4 + 1] = v.y;
                T1[k * T1_STRIDE + c4 + 2] = v.z;
                T1[k * T1_STRIDE + c4 + 3] = v.w;
            }
            __syncthreads();
            #pragma unroll
            for (int i = 0; i < 8; i++) {
                int idx = tid + i * 256;
                int lane = idx & 63, nt = (idx >> 6) & 3, ks = idx >> 8;
                int nl = nt * 16 + (lane & 15);
                int kbase = ks * 32 + (lane >> 4) * 8;
                s16x8 o;
                #pragma unroll
                for (int j = 0; j < 8; j++) o[j] = (short)f2bf(T1[(kbase + j) * T1_STRIDE + nl]);
                *(s16x8*)(dst + (size_t)idx * 8) = o;
            }
        } else {
            float* T2 = (float*)smem;
            const float* src = W2 + ((size_t)e * 1024 + c * 64) * 256;
            #pragma unroll
            for (int p = 0; p < 16; p++) {
                int k2l = p * 4 + (tid >> 6), c4 = (tid & 63) * 4;
                float4 v = *(const float4*)(src + (size_t)k2l * 256 + c4);
                T2[k2l * T2_STRIDE + c4]     = v.x;
                T2[k2l * T2_STRIDE + c4 + 1] = v.y;
                T2[k2l * T2_STRIDE + c4 + 2] = v.z;
                T2[k2l * T2_STRIDE + c4 + 3] = v.w;
            }
            __syncthreads();
            dst += 16384;
            #pragma unroll
            for (int i = 0; i < 8; i++) {
                int idx = tid + i * 256;
                int lane = idx & 63, ntile = (idx >> 6) & 15, ks2 = idx >> 10;
                int n = ntile * 16 + (lane & 15);
                int kbase = ks2 * 32 + (lane >> 4) * 8;
                s16x8 o;
                #pragma unroll
                for (int j = 0; j < 8; j++) o[j] = (short)f2bf(T2[(kbase + j) * T2_STRIDE + n]);
                *(s16x8*)(dst + (size_t)idx * 8) = o;
            }
        }
        return;
    }

    // ---- route + fill role: 64 tokens per block ----
    float* cwS  = (float*)smem;                      // 16 KB
    float* knS  = (float*)(smem + 16384);            // 64 B
    int*   lcnt = (int*)(smem + 16448);              // 64 B
    int*   eIdx = (int*)(smem + 16512);              // 1 KB: [tok_local*4+k]
    float* gV   = (float*)(smem + 17536);            // 1 KB
    int*  lbase = (int*)(smem + 18560);              // 64 B

    int rb = bid - 512;
    int view = rb >> 7, xb = rb & 127;
    const float* src = view == 0 ? v0 : (view == 1 ? v1 : v2);
    for (int i = tid; i < N_EXP * D_MODEL; i += 256)
        cwS[i] = rw[view * N_EXP * D_MODEL + i] + 2.0f * keys[i];
    if (tid < N_EXP) {
        const float4* kp = (const float4*)(keys + tid * D_MODEL);
        float s = 0.f;
        for (int d = 0; d < 64; d++) { float4 k = kp[d]; s += k.x*k.x + k.y*k.y + k.z*k.z + k.w*k.w; }
        knS[tid] = s; lcnt[tid] = 0;
    }
    __syncthreads();

    int wave = tid >> 6, lane = tid & 63;
    for (int t = 0; t < 16; t++) {
        int tl = wave * 16 + t;                      // token local 0..63
        int token = xb * 64 + tl;
        float4 v = ((const float4*)(src + (size_t)token * D_MODEL))[lane];
        ushort4 xo; xo.x = f2bf(v.x); xo.y = f2bf(v.y); xo.z = f2bf(v.z); xo.w = f2bf(v.w);
        ((ushort4*)(Xbf + ((size_t)view * N_TOK + token) * D_MODEL))[lane] = xo;
        float lg[N_EXP];
        #pragma unroll
        for (int e = 0; e < N_EXP; e++) {
            float4 w = *(const float4*)&cwS[e * D_MODEL + lane * 4];
            float p = v.x * w.x + v.y * w.y + v.z * w.z + v.w * w.w;
            #pragma unroll
            for (int s = 32; s > 0; s >>= 1) p += __shfl_xor(p, s, 64);
            lg[e] = p - knS[e];
        }
        int idxs[TOPK]; float vals[TOPK];
        #pragma unroll
        for (int k = 0; k < TOPK; k++) {
            float best = -1e30f; int bi = 0;
            #pragma unroll
            for (int e = 0; e < N_EXP; e++)
                if (lg[e] > best) { best = lg[e]; bi = e; }
            idxs[k] = bi; vals[k] = best;
            #pragma unroll
            for (int e = 0; e < N_EXP; e++)
                lg[e] = (e == bi) ? -1e30f : lg[e];
        }
        float m = vals[0], s = 0.f, ex[TOPK];
        #pragma unroll
        for (int k = 0; k < TOPK; k++) { ex[k] = __expf(vals[k] - m); s += ex[k]; }
        float inv = 1.0f / s;
        if (lane == 0) {
            #pragma unroll
            for (int k = 0; k < TOPK; k++) {
                eIdx[tl * 4 + k] = idxs[k];
                gV[tl * 4 + k] = ex[k] * inv;
                atomicAdd(&lcnt[idxs[k]], 1);
            }
        }
    }
    __syncthreads();
    if (tid < N_EXP)
        lbase[tid] = lcnt[tid] ? atomicAdd(&counts[view * N_EXP + tid], lcnt[tid]) : 0;
    __syncthreads();
    if (tid < N_EXP) {
        int e = tid;
        int dstbase = (view * N_EXP + e) * GCAP + lbase[e];
        int c = 0;
        for (int i = 0; i < 256; i++) {
            if (eIdx[i] == e) {
                rowTok[dstbase + c]  = xb * 64 + (i >> 2);
                rowGate[dstbase + c] = gV[i];
                c++;
            }
        }
    }
}

// ------------------------------------------------------------------
// fused FFN v10: r5/r8 register blocking + restructured K-loop.
//  - W1 double-buffered in LDS (2x32 KB), DMA issued at phase START into the
//    idle buffer -> full phase to land before its draining barrier.
//  - W2 B-frags read DIRECT from global (XCD-affine Wf -> L2 hits): removes
//    64 b128 LDS reads + W2 DMA per chunk, and the second barrier.
//  - Hc double-buffered (2x8 KB): GEMM2(c-1) reads buf (c-1)&1 while
//    GEMM1(c) writes buf c&1.  ONE barrier per phase, 17 total (was 32).
//  - LDS = 65536 + 16384 = 81920 B -> 2 blocks/CU.  tok/gate from global.
// STATIC schedule: xcd = blockIdx&7 owns experts {2x,2x+1} x 3 views.
// ------------------------------------------------------------------
__global__ __launch_bounds__(512, 4) void ffn_kernel(
    const unsigned short* __restrict__ Xbf, const unsigned short* __restrict__ Wf,
    const float* __restrict__ b1, const float* __restrict__ b2,
    const int* __restrict__ counts, const int* __restrict__ rowTok,
    const float* __restrict__ rowGate, float* __restrict__ out)
{
    __shared__ __align__(16) unsigned short W1buf[2][16384];   // 64 KB dbuf
    __shared__ __align__(16) unsigned short Hc[2][4096];       // 16 KB dbuf, A-frag order

    int s = blockIdx.x;
    int xcd = s & 7, k = s >> 3;
    int j = k % 6, ti = k / 6;                 // j: group-of-xcd, ti: tile 0..127
    int e = 2 * xcd + (j & 1), view = j >> 1;
    int g = view * N_EXP + e;
    int L = counts[g];
    int r0 = ti * ROWS;
    if (r0 >= L) return;
    int base = g * GCAP;

    int tid = threadIdx.x;
    int wave = tid >> 6, lane = tid & 63, lmod = lane & 15, quad = lane >> 4;

    const unsigned short* wchunk = Wf + (size_t)e * NCH * REC_ELTS;
    dma_half(wchunk, W1buf[0], wave, lane);      // W1[0] -> buf0

    int mt1 = wave & 3, nh = wave >> 2;          // GEMM1 roles
    int ms  = wave & 1, ns = wave >> 1;          // GEMM2 roles

    // X A-fragments for m-tile mt1 (32 VGPR); tok direct from global
    s16x8 areg[8];
    {
        int gr = r0 + mt1 * 16 + lmod;
        int token = (gr < L) ? rowTok[base + gr] : 0;
        const unsigned short* xp = Xbf + ((size_t)view * N_TOK + token) * D_MODEL;
        #pragma unroll
        for (int ks = 0; ks < 8; ks++)
            areg[ks] = *(const s16x8*)(xp + ks * 32 + quad * 8);
    }

    f32x4 acc2[2][4];
    #pragma unroll
    for (int i = 0; i < 2; i++)
        #pragma unroll
        for (int jj = 0; jj < 4; jj++) acc2[i][jj] = (f32x4){0.f, 0.f, 0.f, 0.f};

    __syncthreads();   // W1[0] landed

    for (int c = 0; c <= NCH; c++) {
        // DMA W1[c+1] into the idle buffer -- has the whole phase to land
        if (c + 1 < NCH)
            dma_half(wchunk + (size_t)(c + 1) * REC_ELTS, W1buf[(c + 1) & 1], wave, lane);
        // W2[c-1] B-frags direct from global (L2); consumed by GEMM2 below
        s16x8 w2r[8];
        if (c > 0) {
            const unsigned short* w2p = wchunk + (size_t)(c - 1) * REC_ELTS + 16384;
            #pragma unroll
            for (int ks2 = 0; ks2 < 2; ks2++)
                #pragma unroll
                for (int nt = 0; nt < 4; nt++)
                    w2r[ks2 * 4 + nt] = *(const s16x8*)(w2p
                        + (size_t)(((ks2 * 16 + ns * 4 + nt) * 64 + lane)) * 8);
        }
        if (c < NCH) {
            // ---- GEMM1(c): 16 rows x 32 cols per wave, K=256
            f32x4 acc1[2];
            acc1[0] = (f32x4){0.f, 0.f, 0.f, 0.f};
            acc1[1] = (f32x4){0.f, 0.f, 0.f, 0.f};
            const unsigned short* w1s = W1buf[c & 1];
            #pragma unroll
            for (int ks = 0; ks < 8; ks++) {
                #pragma unroll
                for (int nt = 0; nt < 2; nt++) {
                    s16x8 b = *(const s16x8*)&w1s[((ks * 4 + nh * 2 + nt) * 64 + lane) * 8];
                    acc1[nt] = __builtin_amdgcn_mfma_f32_16x16x32_bf16(areg[ks], b, acc1[nt], 0, 0, 0);
                }
            }
            // ---- bias + gelu -> Hc[c&1] (A-frag order for GEMM2)
            #pragma unroll
            for (int nt = 0; nt < 2; nt++) {
                float bb = b1[e * HDIM + c * CH + (nh * 2 + nt) * 16 + lmod];
                int qa = nt * 2 + (lmod >> 3);
                int baseo = ((mt1 * 2 + nh) * 16 + qa * 4 + (quad & 3)) * 32 + 0; // placeholder (unused)
                (void)baseo;
                int bo = ((mt1 * 2 + nh) * 64 + qa * 16 + quad * 4) * 8 + (lmod & 7);
                #pragma unroll
                for (int r = 0; r < 4; r++) {
                    float h = acc1[nt][r] + bb;
                    float u = h * (0.7978845608f + 0.0356774081f * h * h);
                    float ex2 = __expf(2.f * u);
                    float tn = 1.f - 2.f * __builtin_amdgcn_rcpf(1.f + ex2);
                    Hc[c & 1][bo + r * 8] = f2bf(0.5f * h * (1.f + tn));
                }
            }
        }
        if (c > 0) {
            // ---- GEMM2(c-1): 32 rows x 64 cols per wave, K=64
            const unsigned short* hs = Hc[(c - 1) & 1];
            #pragma unroll
            for (int ks2 = 0; ks2 < 2; ks2++) {
                s16x8 afr[2];
                #pragma unroll
                for (int mt = 0; mt < 2; mt++)
                    afr[mt] = *(const s16x8*)&hs[(((ms * 2 + mt) * 2 + ks2) * 64 + lane) * 8];
                #pragma unroll
                for (int nt = 0; nt < 4; nt++) {
                    #pragma unroll
                    for (int mt = 0; mt < 2; mt++)
                        acc2[mt][nt] = __builtin_amdgcn_mfma_f32_16x16x32_bf16(
                            afr[mt], w2r[ks2 * 4 + nt], acc2[mt][nt], 0, 0, 0);
                }
            }
        }
        __syncthreads();   // drains W1[c+1] DMA; Hc[c&1] visible; Hc[(c-1)&1] free
    }

    // epilogue: out[token] += gate * (acc2 + b2); tok/gate direct from global
    int   tokR[2][4];
    float gateR[2][4];
    #pragma unroll
    for (int mt = 0; mt < 2; mt++)
        #pragma unroll
        for (int r = 0; r < 4; r++) {
            int gr = r0 + (ms * 2 + mt) * 16 + quad * 4 + r;
            bool ok = gr < L;
            tokR[mt][r]  = ok ? rowTok[base + gr] : -1;
            gateR[mt][r] = ok ? rowGate[base + gr] : 0.f;
        }
    #pragma unroll
    for (int nt = 0; nt < 4; nt++) {
        int col = (ns * 4 + nt) * 16 + lmod;
        float b2v = b2[e * D_MODEL + col];
        #pragma unroll
        for (int mt = 0; mt < 2; mt++) {
            #pragma unroll
            for (int r = 0; r < 4; r++) {
                if (tokR[mt][r] >= 0) {
                    atomicAdd(&out[(size_t)tokR[mt][r] * D_MODEL + col],
                              gateR[mt][r] * (acc2[mt][nt][r] + b2v));
                }
            }
        }
    }
}

// ------------------------------------------------------------------
extern "C" void kernel_launch(void* const* d_in, const int* in_sizes, int n_in,
                              void* d_out, int out_size, void* d_ws, size_t ws_size,
                              hipStream_t stream)
{
    const float* v0   = (const float*)d_in[0];
    const float* v1   = (const float*)d_in[1];
    const float* v2   = (const float*)d_in[2];
    const float* rw   = (const float*)d_in[3];
    const float* keys = (const float*)d_in[4];
    const float* W1   = (const float*)d_in[5];
    const float* b1   = (const float*)d_in[6];
    const float* W2   = (const float*)d_in[7];
    const float* b2   = (const float*)d_in[8];
    float* out = (float*)d_out;

    char* p = (char*)d_ws;
    unsigned short* Xbf = (unsigned short*)p; p += (size_t)N_VIEWS * N_TOK * D_MODEL * 2;
    unsigned short* Wf  = (unsigned short*)p; p += (size_t)N_EXP * NCH * REC_ELTS * 2;
    int*   counts = (int*)p;   p += 256;
    int*   rowTok = (int*)p;   p += (size_t)NGROUP * GCAP * 4;
    float* rowGate= (float*)p; p += (size_t)NGROUP * GCAP * 4;

    hipMemsetAsync(counts, 0, NGROUP * sizeof(int), stream);
    hipMemsetAsync(out, 0, (size_t)out_size * sizeof(float), stream);

    prep_kernel<<<896, 256, 0, stream>>>(v0, v1, v2, rw, keys, W1, W2,
                                         Wf, Xbf, counts, rowTok, rowGate);
    ffn_kernel<<<8 * 768, 512, 0, stream>>>(Xbf, Wf, b1, b2, counts,
                                            rowTok, rowGate, out);
}